// Round 10
// baseline (155.251 us; speedup 1.0000x reference)
//
#include <hip/hip_runtime.h>
#include <hip/hip_bf16.h>
#include <math.h>

#define T_SEQ 4096
#define NBATCH 4
#define C_EMB 512
#define HEAD 64
#define CHUNK 8                  // k-tiles (of 64) per attn phase-1 block
#define EPB 288                  // per batch: sum over qt of ceil((qt+1)/8)

typedef __attribute__((ext_vector_type(8))) short short8;
typedef __attribute__((ext_vector_type(4))) short short4v;
typedef __attribute__((ext_vector_type(4))) float f32x4;

// scale folded into q at projection: exp(s/sqrt(512)) = exp2(qhat . k)
#define C2 (0.044194173824159216f * 1.44269504088896340736f)

__device__ __forceinline__ unsigned short f2bf(float f) {
    union { float f; unsigned u; } v; v.f = f;
    unsigned u = v.u;
    u += 0x7FFF + ((u >> 16) & 1);   // round-to-nearest-even
    return (unsigned short)(u >> 16);
}
// packed f32x2 -> bf16x2 (v_cvt_pk_bf16_f32); low 16 = a, high 16 = b
__device__ __forceinline__ unsigned pk2bf(float a, float b) {
    __hip_bfloat162 h = __float22bfloat162_rn(make_float2(a, b));
    return *(unsigned*)&h;
}
__device__ __forceinline__ float bf2f(unsigned short u) {
    union { unsigned u; float f; } v; v.u = ((unsigned)u) << 16;
    return v.f;
}

// ---------------- W conversion: wt[w*64+n][k] bf16 = W[k][n] ----------------
__global__ __launch_bounds__(64) void wcvt_kernel(
    const float* __restrict__ Wq, const float* __restrict__ Wk,
    const float* __restrict__ Wv, unsigned short* __restrict__ wt)
{
    const int w = blockIdx.x >> 6;
    const int n = blockIdx.x & 63;
    const float* W = (w == 0) ? Wq : (w == 1) ? Wk : Wv;
    const int k0 = threadIdx.x * 8;
    unsigned short tmp[8];
#pragma unroll
    for (int i = 0; i < 8; ++i) tmp[i] = f2bf(W[(size_t)(k0 + i) * HEAD + n]);
    *(short8*)(wt + ((size_t)blockIdx.x) * C_EMB + k0) = *(short8*)tmp;
}

// ---------------- Projection: register-pipelined LDS-free MFMA (R7 form) ------
__device__ __forceinline__ void ld_stage(const float* xp, int s, float4* xr) {
#pragma unroll
    for (int j = 0; j < 4; ++j) {
        xr[2 * j]     = *(const float4*)(xp + (s * 4 + j) * 32);
        xr[2 * j + 1] = *(const float4*)(xp + (s * 4 + j) * 32 + 4);
    }
}

__device__ __forceinline__ void mm_stage(const float4* xr, int s, int l16, int quad,
                                         const unsigned short* __restrict__ wt,
                                         f32x4 acc[3][4]) {
#pragma unroll
    for (int j = 0; j < 4; ++j) {
        const int kc = s * 4 + j;
        float4 a = xr[2 * j], b = xr[2 * j + 1];
        int4 ai = make_int4((int)pk2bf(a.x, a.y), (int)pk2bf(a.z, a.w),
                            (int)pk2bf(b.x, b.y), (int)pk2bf(b.z, b.w));
        short8 af = *(short8*)&ai;
#pragma unroll
        for (int w = 0; w < 3; ++w)
#pragma unroll
            for (int n = 0; n < 4; ++n) {
                short8 bf = *(const short8*)(wt + ((size_t)(w * 64 + n * 16 + l16)) * C_EMB
                                                + kc * 32 + quad * 8);
                acc[w][n] = __builtin_amdgcn_mfma_f32_16x16x32_bf16(af, bf, acc[w][n], 0, 0, 0);
            }
    }
}

__global__ __launch_bounds__(256) void proj_kernel(
    const float* __restrict__ x,            // [16384, 512]
    const unsigned short* __restrict__ wt,  // [192][512] bf16
    unsigned short* __restrict__ qout,      // [16384, 64]  (pre-scaled by C2)
    unsigned short* __restrict__ kout,      // [16384, 64]
    unsigned short* __restrict__ vt)        // [4][64][4096]
{
    __shared__ unsigned short Vsh[64][72];

    const int tid  = threadIdx.x;
    const int wave = tid >> 6;
    const int lane = tid & 63;
    const int l16  = lane & 15;
    const int quad = lane >> 4;
    const int row0 = blockIdx.x * 64;
    const int rowW = row0 + wave * 16 + l16;

    f32x4 acc[3][4];
#pragma unroll
    for (int w = 0; w < 3; ++w)
#pragma unroll
        for (int n = 0; n < 4; ++n) acc[w][n] = (f32x4){0.f, 0.f, 0.f, 0.f};

    const float* xp = x + (size_t)rowW * C_EMB + quad * 8;
    float4 xr[2][8];
    ld_stage(xp, 0, xr[0]);
#pragma unroll
    for (int s = 0; s < 4; ++s) {
        if (s < 3) ld_stage(xp, s + 1, xr[(s + 1) & 1]);
        mm_stage(xr[s & 1], s, l16, quad, wt, acc);
    }

    // q (scaled by C2), k: row-major bf16 stores
#pragma unroll
    for (int n = 0; n < 4; ++n)
#pragma unroll
        for (int r = 0; r < 4; ++r) {
            int row = row0 + wave * 16 + quad * 4 + r;
            qout[(size_t)row * HEAD + n * 16 + l16] = f2bf(acc[0][n][r] * C2);
            kout[(size_t)row * HEAD + n * 16 + l16] = f2bf(acc[1][n][r]);
        }

    // v: transpose 64x64 tile through LDS -> vt[b][h][t]
#pragma unroll
    for (int n = 0; n < 4; ++n)
#pragma unroll
        for (int r = 0; r < 4; ++r)
            Vsh[n * 16 + l16][wave * 16 + quad * 4 + r] = f2bf(acc[2][n][r]);
    __syncthreads();
    {
        int h  = tid >> 2;
        int tc = (tid & 3) * 16;
        int b  = row0 >> 12;
        int t0 = row0 & (T_SEQ - 1);
        unsigned short* dst = vt + ((size_t)(b * HEAD + h)) * T_SEQ + t0 + tc;
        *(short8*)dst       = *(const short8*)&Vsh[h][tc];
        *(short8*)(dst + 8) = *(const short8*)&Vsh[h][tc + 8];
    }
}

// stage one V row-chunk (16 cols from sc) phi-swizzled:
// col c bits [s|d|q1 q0|r1 r0] -> position [s|q1 q0|d|r1 r0]
// so PV B-frags are single contiguous b128 reads matching the A-frag k-order.
__device__ __forceinline__ void stage_v(unsigned short (*Vbuf)[72], int sr, int phiA,
                                        short8 v0, short8 v1) {
    *(short4v*)&Vbuf[sr][phiA]      = __builtin_shufflevector(v0, v0, 0, 1, 2, 3);
    *(short4v*)&Vbuf[sr][phiA + 8]  = __builtin_shufflevector(v0, v0, 4, 5, 6, 7);
    *(short4v*)&Vbuf[sr][phiA + 16] = __builtin_shufflevector(v1, v1, 0, 1, 2, 3);
    *(short4v*)&Vbuf[sr][phiA + 24] = __builtin_shufflevector(v1, v1, 4, 5, 6, 7);
}

// ---------------- Attention phase 1: S^T trick, no P LDS round-trip ----------
__global__ __launch_bounds__(256) void attn1_kernel(
    const unsigned short* __restrict__ qb,  // [B*T, 64] pre-scaled
    const unsigned short* __restrict__ kb,  // [B*T, 64]
    const unsigned short* __restrict__ vt,  // [4][64][4096]
    unsigned short* __restrict__ po,        // [1152][64][64] bf16 partials
    float* __restrict__ pl)                 // [1152][64]
{
    __shared__ unsigned short Ks[2][64][72];    // [buf][kpos][h]
    __shared__ unsigned short Vs[2][64][72];    // [buf][h][phi(kpos)]

    const int tid  = threadIdx.x;
    const int wave = tid >> 6;
    const int lane = tid & 63;
    const int l16  = lane & 15;
    const int quad = lane >> 4;

    const int b = blockIdx.x / EPB;
    const int e = blockIdx.x % EPB;
    // decode e -> (qt, c): group g has qt in [8g,8g+8), nc=g+1, base 4g(g+1)
    int g = 0;
#pragma unroll
    for (int gg = 1; gg < 8; ++gg) if (e >= 4 * gg * (gg + 1)) g = gg;
    const int rem = e - 4 * g * (g + 1);
    const int t   = rem / (g + 1);
    const int c   = rem - t * (g + 1);
    const int qt  = 8 * g + t;

    const size_t base = (size_t)b * T_SEQ;
    const int qrow = qt * 64 + wave * 16 + l16;
    short8 aq0 = *(const short8*)(qb + (base + qrow) * HEAD + quad * 8);
    short8 aq1 = *(const short8*)(qb + (base + qrow) * HEAD + 32 + quad * 8);

    float lacc = 0.f;
    f32x4 o[4];
#pragma unroll
    for (int n = 0; n < 4; ++n) o[n] = (f32x4){0.f, 0.f, 0.f, 0.f};

    const int kt0 = c * CHUNK;
    const int np  = min(CHUNK, qt + 1 - kt0);   // 1..8 64-wide iterations

    const int sr   = tid >> 2;            // 0..63
    const int sc   = (tid & 3) * 16;      // 0,16,32,48
    const int phiA = (sc & 32) + ((sc & 16) >> 2);

    short8 kra, krb, vra, vrb;
    {
        const int kbase = kt0 * 64;
        const unsigned short* ksrc = kb + (base + kbase + sr) * HEAD + sc;
        const unsigned short* vsrc = vt + ((size_t)(b * HEAD + sr)) * T_SEQ + kbase + sc;
        kra = *(const short8*)(ksrc);     krb = *(const short8*)(ksrc + 8);
        vra = *(const short8*)(vsrc);     vrb = *(const short8*)(vsrc + 8);
    }
    *(short8*)&Ks[0][sr][sc]     = kra;  *(short8*)&Ks[0][sr][sc + 8] = krb;
    stage_v(Vs[0], sr, phiA, vra, vrb);

    for (int p = 0; p < np; ++p) {
        const int cur = p & 1;
        const int kbase = (kt0 + p) * 64;
        __syncthreads();                 // LDS[cur] ready; prev-iter reads done

        if (p + 1 < np) {                // prefetch next tile into regs
            const int nb = kbase + 64;
            const unsigned short* ksrc = kb + (base + nb + sr) * HEAD + sc;
            const unsigned short* vsrc = vt + ((size_t)(b * HEAD + sr)) * T_SEQ + nb + sc;
            kra = *(const short8*)(ksrc);  krb = *(const short8*)(ksrc + 8);
            vra = *(const short8*)(vsrc);  vrb = *(const short8*)(vsrc + 8);
        }

        // S^T = K.Q^T: lane gets S[q=l16][c = kbase + n*16 + quad*4 + r]
        f32x4 s[4];
#pragma unroll
        for (int n = 0; n < 4; ++n) {
            short8 bk0 = *(const short8*)&Ks[cur][n * 16 + l16][quad * 8];
            short8 bk1 = *(const short8*)&Ks[cur][n * 16 + l16][32 + quad * 8];
            f32x4 accS = (f32x4){0.f, 0.f, 0.f, 0.f};
            accS = __builtin_amdgcn_mfma_f32_16x16x32_bf16(bk0, aq0, accS, 0, 0, 0);
            accS = __builtin_amdgcn_mfma_f32_16x16x32_bf16(bk1, aq1, accS, 0, 0, 0);
            s[n] = accS;
        }

        // P = exp2(S); zero masked cols on the diagonal tile (wave-uniform test)
#pragma unroll
        for (int n = 0; n < 4; ++n)
#pragma unroll
            for (int r = 0; r < 4; ++r)
                s[n][r] = __builtin_amdgcn_exp2f(s[n][r]);

        if (kbase + 64 > qt * 64) {
            const int cb = kbase + quad * 4;
#pragma unroll
            for (int n = 0; n < 4; ++n)
#pragma unroll
                for (int r = 0; r < 4; ++r)
                    if (cb + n * 16 + r > qrow) s[n][r] = 0.f;
        }

#pragma unroll
        for (int n = 0; n < 4; ++n)
            lacc += (s[n][0] + s[n][1]) + (s[n][2] + s[n][3]);

        // PV: pack A-frag locally (k-order matches phi-swizzled V), B = b128
#pragma unroll
        for (int st = 0; st < 2; ++st) {
            int4 ai = make_int4(
                (int)pk2bf(s[2 * st][0],     s[2 * st][1]),
                (int)pk2bf(s[2 * st][2],     s[2 * st][3]),
                (int)pk2bf(s[2 * st + 1][0], s[2 * st + 1][1]),
                (int)pk2bf(s[2 * st + 1][2], s[2 * st + 1][3]));
            short8 af = *(short8*)&ai;
#pragma unroll
            for (int n = 0; n < 4; ++n) {
                short8 bv = *(const short8*)&Vs[cur][n * 16 + l16][32 * st + quad * 8];
                o[n] = __builtin_amdgcn_mfma_f32_16x16x32_bf16(af, bv, o[n], 0, 0, 0);
            }
        }

        if (p + 1 < np) {                // stage next tile into the other buffer
            const int nxt = cur ^ 1;
            *(short8*)&Ks[nxt][sr][sc]     = kra;  *(short8*)&Ks[nxt][sr][sc + 8] = krb;
            stage_v(Vs[nxt], sr, phiA, vra, vrb);
        }
    }

    // reduce l over the quad dimension (q-row = l16 per lane)
    lacc += __shfl_xor(lacc, 16);
    lacc += __shfl_xor(lacc, 32);

    const int pid = blockIdx.x;
#pragma unroll
    for (int n = 0; n < 4; ++n)
#pragma unroll
        for (int r = 0; r < 4; ++r) {
            int lr = wave * 16 + quad * 4 + r;
            po[(size_t)pid * 4096 + lr * 64 + n * 16 + l16] = f2bf(o[n][r]);
        }
    if (quad == 0)
        pl[pid * 64 + wave * 16 + l16] = lacc;
}

// ---------------- Combine: sum <=8 bf16 partials, normalize ----------------
__global__ __launch_bounds__(256) void combine_kernel(
    const unsigned short* __restrict__ po, const float* __restrict__ pl,
    float* __restrict__ out)
{
    const int gth = blockIdx.x * 256 + threadIdx.x;   // octet index, 131072 total
    const int h8  = gth & 7;
    const int row = gth >> 3;
    const int lr  = row & 63;
    const int qt  = (row >> 6) & 63;
    const int b   = row >> 12;
    const int nc  = (qt >> 3) + 1;
    const int g   = qt >> 3;
    const int rem = qt & 7;
    const int e0  = 4 * g * (g + 1) + rem * (g + 1);
    const int pid0 = b * EPB + e0;

    float l = 0.f;
    float acc[8];
#pragma unroll
    for (int i = 0; i < 8; ++i) acc[i] = 0.f;
    for (int cc = 0; cc < nc; ++cc) {
        l += pl[(pid0 + cc) * 64 + lr];
        short8 p8 = *(const short8*)(po + (size_t)(pid0 + cc) * 4096 + lr * 64 + h8 * 8);
#pragma unroll
        for (int i = 0; i < 8; ++i) acc[i] += bf2f((unsigned short)p8[i]);
    }
    float inv = 1.f / l;
    float4 r0 = make_float4(acc[0] * inv, acc[1] * inv, acc[2] * inv, acc[3] * inv);
    float4 r1 = make_float4(acc[4] * inv, acc[5] * inv, acc[6] * inv, acc[7] * inv);
    float* dst = out + (size_t)gth * 8;
    *(float4*)dst       = r0;
    *(float4*)(dst + 4) = r1;
}

extern "C" void kernel_launch(void* const* d_in, const int* in_sizes, int n_in,
                              void* d_out, int out_size, void* d_ws, size_t ws_size,
                              hipStream_t stream) {
    const float* x  = (const float*)d_in[0];
    const float* Wq = (const float*)d_in[1];
    const float* Wk = (const float*)d_in[2];
    const float* Wv = (const float*)d_in[3];
    float* out = (float*)d_out;

    char* ws = (char*)d_ws;
    unsigned short* qb = (unsigned short*)(ws);                 // 2 MB
    unsigned short* kb = (unsigned short*)(ws + (2u << 20));    // 2 MB
    unsigned short* vt = (unsigned short*)(ws + (4u << 20));    // 2 MB
    unsigned short* wt = (unsigned short*)(ws + (6u << 20));    // 192 KB
    float* pl = (float*)(ws + (6u << 20) + 196608);             // 294912 B
    unsigned short* po = (unsigned short*)(ws + (6u << 20) + 196608 + 294912); // 9.4 MB

    wcvt_kernel<<<dim3(192), dim3(64), 0, stream>>>(Wq, Wk, Wv, wt);
    // MEASUREMENT: proj launched twice (idempotent). dur_R10 - ~126.5 isolates
    // one proj invocation; decides whether R11 rewrites proj or fuses kernels.
    proj_kernel<<<dim3(256), dim3(256), 0, stream>>>(x, wt, qb, kb, vt);
    proj_kernel<<<dim3(256), dim3(256), 0, stream>>>(x, wt, qb, kb, vt);
    attn1_kernel<<<dim3(NBATCH * EPB), dim3(256), 0, stream>>>(qb, kb, vt, po, pl);
    combine_kernel<<<dim3(512), dim3(256), 0, stream>>>(po, pl, out);
}

// Round 11
// 113.434 us; speedup vs baseline: 1.3686x; 1.3686x over previous
//
#include <hip/hip_runtime.h>
#include <hip/hip_bf16.h>
#include <math.h>

#define T_SEQ 4096
#define NBATCH 4
#define C_EMB 512
#define HEAD 64
#define CHUNK 8                  // k-tiles (of 64) per attn phase-1 block
#define EPB 288                  // per batch: sum over qt of ceil((qt+1)/8)

typedef __attribute__((ext_vector_type(8))) short short8;
typedef __attribute__((ext_vector_type(4))) short short4v;
typedef __attribute__((ext_vector_type(4))) float f32x4;

// scale folded into q at projection: exp(s/sqrt(512)) = exp2(qhat . k)
#define C2 (0.044194173824159216f * 1.44269504088896340736f)

__device__ __forceinline__ unsigned short f2bf(float f) {
    union { float f; unsigned u; } v; v.f = f;
    unsigned u = v.u;
    u += 0x7FFF + ((u >> 16) & 1);   // round-to-nearest-even
    return (unsigned short)(u >> 16);
}
// packed f32x2 -> bf16x2 (v_cvt_pk_bf16_f32); low 16 = a, high 16 = b
__device__ __forceinline__ unsigned pk2bf(float a, float b) {
    __hip_bfloat162 h = __float22bfloat162_rn(make_float2(a, b));
    return *(unsigned*)&h;
}
__device__ __forceinline__ float bf2f(unsigned short u) {
    union { unsigned u; float f; } v; v.u = ((unsigned)u) << 16;
    return v.f;
}

// ---------------- W conversion: wt[w*64+n][k] bf16 = W[k][n] ----------------
__global__ __launch_bounds__(64) void wcvt_kernel(
    const float* __restrict__ Wq, const float* __restrict__ Wk,
    const float* __restrict__ Wv, unsigned short* __restrict__ wt)
{
    const int w = blockIdx.x >> 6;
    const int n = blockIdx.x & 63;
    const float* W = (w == 0) ? Wq : (w == 1) ? Wk : Wv;
    const int k0 = threadIdx.x * 8;
    unsigned short tmp[8];
#pragma unroll
    for (int i = 0; i < 8; ++i) tmp[i] = f2bf(W[(size_t)(k0 + i) * HEAD + n]);
    *(short8*)(wt + ((size_t)blockIdx.x) * C_EMB + k0) = *(short8*)tmp;
}

// ---------------- Projection v3: LDS-staged W, 2 blocks/CU --------------------
// grid 512 x 256; block = 32 x-rows. K processed in 8 chunks of 64, W-tile
// [192][64] + x-tile [32][64](bf16) double-buffered in LDS (row stride 72:
// 4-bank shift/row -> 2-way conflicts = free). Waves column-split the 12
// output tiles (3 each) — B comes from LDS so no duplicated global traffic.
__global__ __launch_bounds__(256) void proj_kernel(
    const float* __restrict__ x,            // [16384, 512]
    const unsigned short* __restrict__ wt,  // [192][512] bf16
    unsigned short* __restrict__ qout,      // [16384, 64]  (pre-scaled by C2)
    unsigned short* __restrict__ kout,      // [16384, 64]
    unsigned short* __restrict__ vt)        // [4][64][4096]
{
    __shared__ unsigned short Wl[2][192][72];   // 55296 B
    __shared__ unsigned short Xl[2][32][72];    //  9216 B
    __shared__ unsigned short Vsh[64][40];      //  5120 B

    const int tid  = threadIdx.x;
    const int wave = tid >> 6;
    const int lane = tid & 63;
    const int l16  = lane & 15;
    const int quad = lane >> 4;
    const int row0 = blockIdx.x * 32;

    // staging maps
    const int wrow0 = tid >> 3;          // W: thread handles rows wrow0 + m*32
    const int wsc   = (tid & 7) * 8;     //    col segment (8 shorts)
    const int xrow  = tid >> 3;          // x: row 0..31
    const int xc8   = (tid & 7) * 8;     //    8-float group

    f32x4 acc[3][2];
#pragma unroll
    for (int j = 0; j < 3; ++j)
#pragma unroll
        for (int rh = 0; rh < 2; ++rh) acc[j][rh] = (f32x4){0.f, 0.f, 0.f, 0.f};

    // ---- stage chunk 0 into buffer 0 ----
#pragma unroll
    for (int m = 0; m < 6; ++m) {
        int row = wrow0 + m * 32;
        short8 w8 = *(const short8*)(wt + (size_t)row * C_EMB + wsc);
        *(short8*)&Wl[0][row][wsc] = w8;
    }
    {
        const float* xs = x + (size_t)(row0 + xrow) * C_EMB + xc8;
        float4 a = *(const float4*)(xs);
        float4 b = *(const float4*)(xs + 4);
        int4 ai = make_int4((int)pk2bf(a.x, a.y), (int)pk2bf(a.z, a.w),
                            (int)pk2bf(b.x, b.y), (int)pk2bf(b.z, b.w));
        *(short8*)&Xl[0][xrow][xc8] = *(short8*)&ai;
    }
    __syncthreads();

    for (int c = 0; c < 8; ++c) {
        const int bb = c & 1;
        if (c < 7) {                     // stage chunk c+1 into other buffer
            const int nb = bb ^ 1;
            const int kc0 = (c + 1) * 64;
#pragma unroll
            for (int m = 0; m < 6; ++m) {
                int row = wrow0 + m * 32;
                short8 w8 = *(const short8*)(wt + (size_t)row * C_EMB + kc0 + wsc);
                *(short8*)&Wl[nb][row][wsc] = w8;
            }
            const float* xs = x + (size_t)(row0 + xrow) * C_EMB + kc0 + xc8;
            float4 a = *(const float4*)(xs);
            float4 b = *(const float4*)(xs + 4);
            int4 ai = make_int4((int)pk2bf(a.x, a.y), (int)pk2bf(a.z, a.w),
                                (int)pk2bf(b.x, b.y), (int)pk2bf(b.z, b.w));
            *(short8*)&Xl[nb][xrow][xc8] = *(short8*)&ai;
        }

        // compute on buffer bb: 2 kc x (2 A-frags, 3 B-frags, 6 MFMA)
#pragma unroll
        for (int kc = 0; kc < 2; ++kc) {
            short8 a0 = *(const short8*)&Xl[bb][l16][kc * 32 + quad * 8];
            short8 a1 = *(const short8*)&Xl[bb][16 + l16][kc * 32 + quad * 8];
#pragma unroll
            for (int j = 0; j < 3; ++j) {
                const int ct = wave * 3 + j;
                short8 bfr = *(const short8*)&Wl[bb][ct * 16 + l16][kc * 32 + quad * 8];
                acc[j][0] = __builtin_amdgcn_mfma_f32_16x16x32_bf16(a0, bfr, acc[j][0], 0, 0, 0);
                acc[j][1] = __builtin_amdgcn_mfma_f32_16x16x32_bf16(a1, bfr, acc[j][1], 0, 0, 0);
            }
        }
        __syncthreads();
    }

    // epilogue: wave owns col-tiles 3w..3w+2; tile ct: m=ct>>2 (q/k/v), n=ct&3
#pragma unroll
    for (int j = 0; j < 3; ++j) {
        const int ct = wave * 3 + j;
        const int m  = ct >> 2;
        const int n  = ct & 3;
#pragma unroll
        for (int rh = 0; rh < 2; ++rh)
#pragma unroll
            for (int r = 0; r < 4; ++r) {
                const int row = row0 + rh * 16 + quad * 4 + r;
                if (m == 0)
                    qout[(size_t)row * HEAD + n * 16 + l16] = f2bf(acc[j][rh][r] * C2);
                else if (m == 1)
                    kout[(size_t)row * HEAD + n * 16 + l16] = f2bf(acc[j][rh][r]);
                else
                    Vsh[n * 16 + l16][rh * 16 + quad * 4 + r] = f2bf(acc[j][rh][r]);
            }
    }
    __syncthreads();
    {
        int h  = tid >> 2;
        int tc = (tid & 3) * 8;
        int b  = row0 >> 12;
        int t0 = row0 & (T_SEQ - 1);
        unsigned short* dst = vt + ((size_t)(b * HEAD + h)) * T_SEQ + t0 + tc;
        *(short8*)dst = *(const short8*)&Vsh[h][tc];
    }
}

// stage one V row-chunk (16 cols from sc) phi-swizzled:
// col c bits [s|d|q1 q0|r1 r0] -> position [s|q1 q0|d|r1 r0]
// so PV B-frags are single contiguous b128 reads matching the A-frag k-order.
__device__ __forceinline__ void stage_v(unsigned short (*Vbuf)[72], int sr, int phiA,
                                        short8 v0, short8 v1) {
    *(short4v*)&Vbuf[sr][phiA]      = __builtin_shufflevector(v0, v0, 0, 1, 2, 3);
    *(short4v*)&Vbuf[sr][phiA + 8]  = __builtin_shufflevector(v0, v0, 4, 5, 6, 7);
    *(short4v*)&Vbuf[sr][phiA + 16] = __builtin_shufflevector(v1, v1, 0, 1, 2, 3);
    *(short4v*)&Vbuf[sr][phiA + 24] = __builtin_shufflevector(v1, v1, 4, 5, 6, 7);
}

// ---------------- Attention phase 1: S^T trick, no P LDS round-trip ----------
__global__ __launch_bounds__(256) void attn1_kernel(
    const unsigned short* __restrict__ qb,  // [B*T, 64] pre-scaled
    const unsigned short* __restrict__ kb,  // [B*T, 64]
    const unsigned short* __restrict__ vt,  // [4][64][4096]
    unsigned short* __restrict__ po,        // [1152][64][64] bf16 partials
    float* __restrict__ pl)                 // [1152][64]
{
    __shared__ unsigned short Ks[2][64][72];    // [buf][kpos][h]
    __shared__ unsigned short Vs[2][64][72];    // [buf][h][phi(kpos)]

    const int tid  = threadIdx.x;
    const int wave = tid >> 6;
    const int lane = tid & 63;
    const int l16  = lane & 15;
    const int quad = lane >> 4;

    const int b = blockIdx.x / EPB;
    const int e = blockIdx.x % EPB;
    // decode e -> (qt, c): group g has qt in [8g,8g+8), nc=g+1, base 4g(g+1)
    int g = 0;
#pragma unroll
    for (int gg = 1; gg < 8; ++gg) if (e >= 4 * gg * (gg + 1)) g = gg;
    const int rem = e - 4 * g * (g + 1);
    const int t   = rem / (g + 1);
    const int c   = rem - t * (g + 1);
    const int qt  = 8 * g + t;

    const size_t base = (size_t)b * T_SEQ;
    const int qrow = qt * 64 + wave * 16 + l16;
    short8 aq0 = *(const short8*)(qb + (base + qrow) * HEAD + quad * 8);
    short8 aq1 = *(const short8*)(qb + (base + qrow) * HEAD + 32 + quad * 8);

    float lacc = 0.f;
    f32x4 o[4];
#pragma unroll
    for (int n = 0; n < 4; ++n) o[n] = (f32x4){0.f, 0.f, 0.f, 0.f};

    const int kt0 = c * CHUNK;
    const int np  = min(CHUNK, qt + 1 - kt0);   // 1..8 64-wide iterations

    const int sr   = tid >> 2;            // 0..63
    const int sc   = (tid & 3) * 16;      // 0,16,32,48
    const int phiA = (sc & 32) + ((sc & 16) >> 2);

    short8 kra, krb, vra, vrb;
    {
        const int kbase = kt0 * 64;
        const unsigned short* ksrc = kb + (base + kbase + sr) * HEAD + sc;
        const unsigned short* vsrc = vt + ((size_t)(b * HEAD + sr)) * T_SEQ + kbase + sc;
        kra = *(const short8*)(ksrc);     krb = *(const short8*)(ksrc + 8);
        vra = *(const short8*)(vsrc);     vrb = *(const short8*)(vsrc + 8);
    }
    *(short8*)&Ks[0][sr][sc]     = kra;  *(short8*)&Ks[0][sr][sc + 8] = krb;
    stage_v(Vs[0], sr, phiA, vra, vrb);

    for (int p = 0; p < np; ++p) {
        const int cur = p & 1;
        const int kbase = (kt0 + p) * 64;
        __syncthreads();                 // LDS[cur] ready; prev-iter reads done

        if (p + 1 < np) {                // prefetch next tile into regs
            const int nb = kbase + 64;
            const unsigned short* ksrc = kb + (base + nb + sr) * HEAD + sc;
            const unsigned short* vsrc = vt + ((size_t)(b * HEAD + sr)) * T_SEQ + nb + sc;
            kra = *(const short8*)(ksrc);  krb = *(const short8*)(ksrc + 8);
            vra = *(const short8*)(vsrc);  vrb = *(const short8*)(vsrc + 8);
        }

        // S^T = K.Q^T: lane gets S[q=l16][c = kbase + n*16 + quad*4 + r]
        f32x4 s[4];
#pragma unroll
        for (int n = 0; n < 4; ++n) {
            short8 bk0 = *(const short8*)&Ks[cur][n * 16 + l16][quad * 8];
            short8 bk1 = *(const short8*)&Ks[cur][n * 16 + l16][32 + quad * 8];
            f32x4 accS = (f32x4){0.f, 0.f, 0.f, 0.f};
            accS = __builtin_amdgcn_mfma_f32_16x16x32_bf16(bk0, aq0, accS, 0, 0, 0);
            accS = __builtin_amdgcn_mfma_f32_16x16x32_bf16(bk1, aq1, accS, 0, 0, 0);
            s[n] = accS;
        }

        // P = exp2(S); zero masked cols on the diagonal tile (wave-uniform test)
#pragma unroll
        for (int n = 0; n < 4; ++n)
#pragma unroll
            for (int r = 0; r < 4; ++r)
                s[n][r] = __builtin_amdgcn_exp2f(s[n][r]);

        if (kbase + 64 > qt * 64) {
            const int cb = kbase + quad * 4;
#pragma unroll
            for (int n = 0; n < 4; ++n)
#pragma unroll
                for (int r = 0; r < 4; ++r)
                    if (cb + n * 16 + r > qrow) s[n][r] = 0.f;
        }

#pragma unroll
        for (int n = 0; n < 4; ++n)
            lacc += (s[n][0] + s[n][1]) + (s[n][2] + s[n][3]);

        // PV: pack A-frag locally (k-order matches phi-swizzled V), B = b128
#pragma unroll
        for (int st = 0; st < 2; ++st) {
            int4 ai = make_int4(
                (int)pk2bf(s[2 * st][0],     s[2 * st][1]),
                (int)pk2bf(s[2 * st][2],     s[2 * st][3]),
                (int)pk2bf(s[2 * st + 1][0], s[2 * st + 1][1]),
                (int)pk2bf(s[2 * st + 1][2], s[2 * st + 1][3]));
            short8 af = *(short8*)&ai;
#pragma unroll
            for (int n = 0; n < 4; ++n) {
                short8 bv = *(const short8*)&Vs[cur][n * 16 + l16][32 * st + quad * 8];
                o[n] = __builtin_amdgcn_mfma_f32_16x16x32_bf16(af, bv, o[n], 0, 0, 0);
            }
        }

        if (p + 1 < np) {                // stage next tile into the other buffer
            const int nxt = cur ^ 1;
            *(short8*)&Ks[nxt][sr][sc]     = kra;  *(short8*)&Ks[nxt][sr][sc + 8] = krb;
            stage_v(Vs[nxt], sr, phiA, vra, vrb);
        }
    }

    // reduce l over the quad dimension (q-row = l16 per lane)
    lacc += __shfl_xor(lacc, 16);
    lacc += __shfl_xor(lacc, 32);

    const int pid = blockIdx.x;
#pragma unroll
    for (int n = 0; n < 4; ++n)
#pragma unroll
        for (int r = 0; r < 4; ++r) {
            int lr = wave * 16 + quad * 4 + r;
            po[(size_t)pid * 4096 + lr * 64 + n * 16 + l16] = f2bf(o[n][r]);
        }
    if (quad == 0)
        pl[pid * 64 + wave * 16 + l16] = lacc;
}

// ---------------- Combine: sum <=8 bf16 partials, normalize ----------------
__global__ __launch_bounds__(256) void combine_kernel(
    const unsigned short* __restrict__ po, const float* __restrict__ pl,
    float* __restrict__ out)
{
    const int gth = blockIdx.x * 256 + threadIdx.x;   // octet index, 131072 total
    const int h8  = gth & 7;
    const int row = gth >> 3;
    const int lr  = row & 63;
    const int qt  = (row >> 6) & 63;
    const int b   = row >> 12;
    const int nc  = (qt >> 3) + 1;
    const int g   = qt >> 3;
    const int rem = qt & 7;
    const int e0  = 4 * g * (g + 1) + rem * (g + 1);
    const int pid0 = b * EPB + e0;

    float l = 0.f;
    float acc[8];
#pragma unroll
    for (int i = 0; i < 8; ++i) acc[i] = 0.f;
    for (int cc = 0; cc < nc; ++cc) {
        l += pl[(pid0 + cc) * 64 + lr];
        short8 p8 = *(const short8*)(po + (size_t)(pid0 + cc) * 4096 + lr * 64 + h8 * 8);
#pragma unroll
        for (int i = 0; i < 8; ++i) acc[i] += bf2f((unsigned short)p8[i]);
    }
    float inv = 1.f / l;
    float4 r0 = make_float4(acc[0] * inv, acc[1] * inv, acc[2] * inv, acc[3] * inv);
    float4 r1 = make_float4(acc[4] * inv, acc[5] * inv, acc[6] * inv, acc[7] * inv);
    float* dst = out + (size_t)gth * 8;
    *(float4*)dst       = r0;
    *(float4*)(dst + 4) = r1;
}

extern "C" void kernel_launch(void* const* d_in, const int* in_sizes, int n_in,
                              void* d_out, int out_size, void* d_ws, size_t ws_size,
                              hipStream_t stream) {
    const float* x  = (const float*)d_in[0];
    const float* Wq = (const float*)d_in[1];
    const float* Wk = (const float*)d_in[2];
    const float* Wv = (const float*)d_in[3];
    float* out = (float*)d_out;

    char* ws = (char*)d_ws;
    unsigned short* qb = (unsigned short*)(ws);                 // 2 MB
    unsigned short* kb = (unsigned short*)(ws + (2u << 20));    // 2 MB
    unsigned short* vt = (unsigned short*)(ws + (4u << 20));    // 2 MB
    unsigned short* wt = (unsigned short*)(ws + (6u << 20));    // 192 KB
    float* pl = (float*)(ws + (6u << 20) + 196608);             // 294912 B
    unsigned short* po = (unsigned short*)(ws + (6u << 20) + 196608 + 294912); // 9.4 MB

    wcvt_kernel<<<dim3(192), dim3(64), 0, stream>>>(Wq, Wk, Wv, wt);
    proj_kernel<<<dim3(512), dim3(256), 0, stream>>>(x, wt, qb, kb, vt);
    attn1_kernel<<<dim3(NBATCH * EPB), dim3(256), 0, stream>>>(qb, kb, vt, po, pl);
    combine_kernel<<<dim3(512), dim3(256), 0, stream>>>(po, pl, out);
}

// Round 12
// 112.915 us; speedup vs baseline: 1.3749x; 1.0046x over previous
//
#include <hip/hip_runtime.h>
#include <hip/hip_bf16.h>
#include <math.h>

#define T_SEQ 4096
#define NBATCH 4
#define C_EMB 512
#define HEAD 64
#define CHUNK 8                  // k-tiles (of 64) per attn phase-1 block
#define EPB 288                  // per batch: sum over qt of ceil((qt+1)/8)

typedef __attribute__((ext_vector_type(8))) short short8;
typedef __attribute__((ext_vector_type(4))) short short4v;
typedef __attribute__((ext_vector_type(4))) float f32x4;

// scale folded into q at projection: exp(s/sqrt(512)) = exp2(qhat . k)
#define C2 (0.044194173824159216f * 1.44269504088896340736f)

__device__ __forceinline__ unsigned short f2bf(float f) {
    union { float f; unsigned u; } v; v.f = f;
    unsigned u = v.u;
    u += 0x7FFF + ((u >> 16) & 1);   // round-to-nearest-even
    return (unsigned short)(u >> 16);
}
// packed f32x2 -> bf16x2 (v_cvt_pk_bf16_f32); low 16 = a, high 16 = b
__device__ __forceinline__ unsigned pk2bf(float a, float b) {
    __hip_bfloat162 h = __float22bfloat162_rn(make_float2(a, b));
    return *(unsigned*)&h;
}
__device__ __forceinline__ float bf2f(unsigned short u) {
    union { unsigned u; float f; } v; v.u = ((unsigned)u) << 16;
    return v.f;
}

// ---------------- W conversion: wt[w*64+n][k] bf16 = W[k][n] ----------------
__global__ __launch_bounds__(64) void wcvt_kernel(
    const float* __restrict__ Wq, const float* __restrict__ Wk,
    const float* __restrict__ Wv, unsigned short* __restrict__ wt)
{
    const int w = blockIdx.x >> 6;
    const int n = blockIdx.x & 63;
    const float* W = (w == 0) ? Wq : (w == 1) ? Wk : Wv;
    const int k0 = threadIdx.x * 8;
    unsigned short tmp[8];
#pragma unroll
    for (int i = 0; i < 8; ++i) tmp[i] = f2bf(W[(size_t)(k0 + i) * HEAD + n]);
    *(short8*)(wt + ((size_t)blockIdx.x) * C_EMB + k0) = *(short8*)tmp;
}

// ---------------- Projection v4: LDS-staged W, 512 threads, 16 waves/CU -------
// grid 512 x 512thr; block = 32 x-rows, 2 blocks/CU (LDS 64.5 KB). 8 waves
// split the 24 (M-quarter x N-tile) jobs 3 each: wave w -> mq=w&1 (16 rows),
// N-tiles 3*(w>>1)..+2. K in 8 chunks of 64, W/x double-buffered; Vsh aliases
// Xl after the K-loop (dead space) to keep 2 blocks/CU.
__global__ __launch_bounds__(512, 4) void proj_kernel(
    const float* __restrict__ x,            // [16384, 512]
    const unsigned short* __restrict__ wt,  // [192][512] bf16
    unsigned short* __restrict__ qout,      // [16384, 64]  (pre-scaled by C2)
    unsigned short* __restrict__ kout,      // [16384, 64]
    unsigned short* __restrict__ vt)        // [4][64][4096]
{
    __shared__ unsigned short Wl[2][192][72];   // 55296 B
    __shared__ unsigned short Xl[2][32][72];    //  9216 B (reused as Vsh[64][40])

    const int tid  = threadIdx.x;
    const int wave = tid >> 6;
    const int lane = tid & 63;
    const int l16  = lane & 15;
    const int quad = lane >> 4;
    const int row0 = blockIdx.x * 32;
    const int mq   = wave & 1;           // M-quarter (16 rows)
    const int ng   = wave >> 1;          // N-group: tiles ng*3 .. ng*3+2

    // staging maps
    const int wrow = tid >> 3;           // W rows wrow + m*64, m=0..2
    const int wsc  = (tid & 7) * 8;
    const bool xst = tid < 256;
    const int xrow = tid >> 3;           // x row (tid<256)
    const int xc8  = (tid & 7) * 8;

    f32x4 acc[3];
#pragma unroll
    for (int j = 0; j < 3; ++j) acc[j] = (f32x4){0.f, 0.f, 0.f, 0.f};

    // ---- stage chunk 0 into buffer 0 ----
#pragma unroll
    for (int m = 0; m < 3; ++m) {
        int row = wrow + m * 64;
        *(short8*)&Wl[0][row][wsc] = *(const short8*)(wt + (size_t)row * C_EMB + wsc);
    }
    if (xst) {
        const float* xs = x + (size_t)(row0 + xrow) * C_EMB + xc8;
        float4 a = *(const float4*)(xs);
        float4 b = *(const float4*)(xs + 4);
        int4 ai = make_int4((int)pk2bf(a.x, a.y), (int)pk2bf(a.z, a.w),
                            (int)pk2bf(b.x, b.y), (int)pk2bf(b.z, b.w));
        *(short8*)&Xl[0][xrow][xc8] = *(short8*)&ai;
    }
    __syncthreads();

    for (int c = 0; c < 8; ++c) {
        const int bb = c & 1;
        if (c < 7) {                     // stage chunk c+1 into other buffer
            const int nb = bb ^ 1;
            const int kc0 = (c + 1) * 64;
#pragma unroll
            for (int m = 0; m < 3; ++m) {
                int row = wrow + m * 64;
                *(short8*)&Wl[nb][row][wsc] =
                    *(const short8*)(wt + (size_t)row * C_EMB + kc0 + wsc);
            }
            if (xst) {
                const float* xs = x + (size_t)(row0 + xrow) * C_EMB + kc0 + xc8;
                float4 a = *(const float4*)(xs);
                float4 b = *(const float4*)(xs + 4);
                int4 ai = make_int4((int)pk2bf(a.x, a.y), (int)pk2bf(a.z, a.w),
                                    (int)pk2bf(b.x, b.y), (int)pk2bf(b.z, b.w));
                *(short8*)&Xl[nb][xrow][xc8] = *(short8*)&ai;
            }
        }

        // compute on buffer bb: 2 kc x (1 A-frag, 3 B-frags, 3 MFMA)
#pragma unroll
        for (int kc = 0; kc < 2; ++kc) {
            short8 a0 = *(const short8*)&Xl[bb][mq * 16 + l16][kc * 32 + quad * 8];
#pragma unroll
            for (int j = 0; j < 3; ++j) {
                const int ct = ng * 3 + j;
                short8 bfr = *(const short8*)&Wl[bb][ct * 16 + l16][kc * 32 + quad * 8];
                acc[j] = __builtin_amdgcn_mfma_f32_16x16x32_bf16(a0, bfr, acc[j], 0, 0, 0);
            }
        }
        __syncthreads();
    }

    // epilogue: wave owns (mq, tiles ng*3..ng*3+2); tile ct: m=ct>>2, n=ct&3
    unsigned short (*Vsh)[40] = (unsigned short (*)[40]) & Xl[0][0][0];  // 5120 B
#pragma unroll
    for (int j = 0; j < 3; ++j) {
        const int ct = ng * 3 + j;
        const int m  = ct >> 2;
        const int n  = ct & 3;
#pragma unroll
        for (int r = 0; r < 4; ++r) {
            const int row = row0 + mq * 16 + quad * 4 + r;
            if (m == 0)
                qout[(size_t)row * HEAD + n * 16 + l16] = f2bf(acc[j][r] * C2);
            else if (m == 1)
                kout[(size_t)row * HEAD + n * 16 + l16] = f2bf(acc[j][r]);
            else
                Vsh[n * 16 + l16][mq * 16 + quad * 4 + r] = f2bf(acc[j][r]);
        }
    }
    __syncthreads();
    if (tid < 256) {
        int h  = tid >> 2;
        int tc = (tid & 3) * 8;
        int b  = row0 >> 12;
        int t0 = row0 & (T_SEQ - 1);
        unsigned short* dst = vt + ((size_t)(b * HEAD + h)) * T_SEQ + t0 + tc;
        *(short8*)dst = *(const short8*)&Vsh[h][tc];
    }
}

// stage one V row-chunk (16 cols from sc) phi-swizzled:
// col c bits [s|d|q1 q0|r1 r0] -> position [s|q1 q0|d|r1 r0]
// so PV B-frags are single contiguous b128 reads matching the A-frag k-order.
__device__ __forceinline__ void stage_v(unsigned short (*Vbuf)[72], int sr, int phiA,
                                        short8 v0, short8 v1) {
    *(short4v*)&Vbuf[sr][phiA]      = __builtin_shufflevector(v0, v0, 0, 1, 2, 3);
    *(short4v*)&Vbuf[sr][phiA + 8]  = __builtin_shufflevector(v0, v0, 4, 5, 6, 7);
    *(short4v*)&Vbuf[sr][phiA + 16] = __builtin_shufflevector(v1, v1, 0, 1, 2, 3);
    *(short4v*)&Vbuf[sr][phiA + 24] = __builtin_shufflevector(v1, v1, 4, 5, 6, 7);
}

// ---------------- Attention phase 1: S^T trick, no P LDS round-trip ----------
__global__ __launch_bounds__(256) void attn1_kernel(
    const unsigned short* __restrict__ qb,  // [B*T, 64] pre-scaled
    const unsigned short* __restrict__ kb,  // [B*T, 64]
    const unsigned short* __restrict__ vt,  // [4][64][4096]
    unsigned short* __restrict__ po,        // [1152][64][64] bf16 partials
    float* __restrict__ pl)                 // [1152][64]
{
    __shared__ unsigned short Ks[2][64][72];    // [buf][kpos][h]
    __shared__ unsigned short Vs[2][64][72];    // [buf][h][phi(kpos)]

    const int tid  = threadIdx.x;
    const int wave = tid >> 6;
    const int lane = tid & 63;
    const int l16  = lane & 15;
    const int quad = lane >> 4;

    const int b = blockIdx.x / EPB;
    const int e = blockIdx.x % EPB;
    // decode e -> (qt, c): group g has qt in [8g,8g+8), nc=g+1, base 4g(g+1)
    int g = 0;
#pragma unroll
    for (int gg = 1; gg < 8; ++gg) if (e >= 4 * gg * (gg + 1)) g = gg;
    const int rem = e - 4 * g * (g + 1);
    const int t   = rem / (g + 1);
    const int c   = rem - t * (g + 1);
    const int qt  = 8 * g + t;

    const size_t base = (size_t)b * T_SEQ;
    const int qrow = qt * 64 + wave * 16 + l16;
    short8 aq0 = *(const short8*)(qb + (base + qrow) * HEAD + quad * 8);
    short8 aq1 = *(const short8*)(qb + (base + qrow) * HEAD + 32 + quad * 8);

    float lacc = 0.f;
    f32x4 o[4];
#pragma unroll
    for (int n = 0; n < 4; ++n) o[n] = (f32x4){0.f, 0.f, 0.f, 0.f};

    const int kt0 = c * CHUNK;
    const int np  = min(CHUNK, qt + 1 - kt0);   // 1..8 64-wide iterations

    const int sr   = tid >> 2;            // 0..63
    const int sc   = (tid & 3) * 16;      // 0,16,32,48
    const int phiA = (sc & 32) + ((sc & 16) >> 2);

    short8 kra, krb, vra, vrb;
    {
        const int kbase = kt0 * 64;
        const unsigned short* ksrc = kb + (base + kbase + sr) * HEAD + sc;
        const unsigned short* vsrc = vt + ((size_t)(b * HEAD + sr)) * T_SEQ + kbase + sc;
        kra = *(const short8*)(ksrc);     krb = *(const short8*)(ksrc + 8);
        vra = *(const short8*)(vsrc);     vrb = *(const short8*)(vsrc + 8);
    }
    *(short8*)&Ks[0][sr][sc]     = kra;  *(short8*)&Ks[0][sr][sc + 8] = krb;
    stage_v(Vs[0], sr, phiA, vra, vrb);

    for (int p = 0; p < np; ++p) {
        const int cur = p & 1;
        const int kbase = (kt0 + p) * 64;
        __syncthreads();                 // LDS[cur] ready; prev-iter reads done

        if (p + 1 < np) {                // prefetch next tile into regs
            const int nb = kbase + 64;
            const unsigned short* ksrc = kb + (base + nb + sr) * HEAD + sc;
            const unsigned short* vsrc = vt + ((size_t)(b * HEAD + sr)) * T_SEQ + nb + sc;
            kra = *(const short8*)(ksrc);  krb = *(const short8*)(ksrc + 8);
            vra = *(const short8*)(vsrc);  vrb = *(const short8*)(vsrc + 8);
        }

        // S^T = K.Q^T: lane gets S[q=l16][c = kbase + n*16 + quad*4 + r]
        f32x4 s[4];
#pragma unroll
        for (int n = 0; n < 4; ++n) {
            short8 bk0 = *(const short8*)&Ks[cur][n * 16 + l16][quad * 8];
            short8 bk1 = *(const short8*)&Ks[cur][n * 16 + l16][32 + quad * 8];
            f32x4 accS = (f32x4){0.f, 0.f, 0.f, 0.f};
            accS = __builtin_amdgcn_mfma_f32_16x16x32_bf16(bk0, aq0, accS, 0, 0, 0);
            accS = __builtin_amdgcn_mfma_f32_16x16x32_bf16(bk1, aq1, accS, 0, 0, 0);
            s[n] = accS;
        }

        // P = exp2(S); zero masked cols on the diagonal tile (wave-uniform test)
#pragma unroll
        for (int n = 0; n < 4; ++n)
#pragma unroll
            for (int r = 0; r < 4; ++r)
                s[n][r] = __builtin_amdgcn_exp2f(s[n][r]);

        if (kbase + 64 > qt * 64) {
            const int cb = kbase + quad * 4;
#pragma unroll
            for (int n = 0; n < 4; ++n)
#pragma unroll
                for (int r = 0; r < 4; ++r)
                    if (cb + n * 16 + r > qrow) s[n][r] = 0.f;
        }

#pragma unroll
        for (int n = 0; n < 4; ++n)
            lacc += (s[n][0] + s[n][1]) + (s[n][2] + s[n][3]);

        // PV: pack A-frag locally (k-order matches phi-swizzled V), B = b128
#pragma unroll
        for (int st = 0; st < 2; ++st) {
            int4 ai = make_int4(
                (int)pk2bf(s[2 * st][0],     s[2 * st][1]),
                (int)pk2bf(s[2 * st][2],     s[2 * st][3]),
                (int)pk2bf(s[2 * st + 1][0], s[2 * st + 1][1]),
                (int)pk2bf(s[2 * st + 1][2], s[2 * st + 1][3]));
            short8 af = *(short8*)&ai;
#pragma unroll
            for (int n = 0; n < 4; ++n) {
                short8 bv = *(const short8*)&Vs[cur][n * 16 + l16][32 * st + quad * 8];
                o[n] = __builtin_amdgcn_mfma_f32_16x16x32_bf16(af, bv, o[n], 0, 0, 0);
            }
        }

        if (p + 1 < np) {                // stage next tile into the other buffer
            const int nxt = cur ^ 1;
            *(short8*)&Ks[nxt][sr][sc]     = kra;  *(short8*)&Ks[nxt][sr][sc + 8] = krb;
            stage_v(Vs[nxt], sr, phiA, vra, vrb);
        }
    }

    // reduce l over the quad dimension (q-row = l16 per lane)
    lacc += __shfl_xor(lacc, 16);
    lacc += __shfl_xor(lacc, 32);

    const int pid = blockIdx.x;
#pragma unroll
    for (int n = 0; n < 4; ++n)
#pragma unroll
        for (int r = 0; r < 4; ++r) {
            int lr = wave * 16 + quad * 4 + r;
            po[(size_t)pid * 4096 + lr * 64 + n * 16 + l16] = f2bf(o[n][r]);
        }
    if (quad == 0)
        pl[pid * 64 + wave * 16 + l16] = lacc;
}

// ---------------- Combine: sum <=8 bf16 partials, normalize ----------------
__global__ __launch_bounds__(256) void combine_kernel(
    const unsigned short* __restrict__ po, const float* __restrict__ pl,
    float* __restrict__ out)
{
    const int gth = blockIdx.x * 256 + threadIdx.x;   // octet index, 131072 total
    const int h8  = gth & 7;
    const int row = gth >> 3;
    const int lr  = row & 63;
    const int qt  = (row >> 6) & 63;
    const int b   = row >> 12;
    const int nc  = (qt >> 3) + 1;
    const int g   = qt >> 3;
    const int rem = qt & 7;
    const int e0  = 4 * g * (g + 1) + rem * (g + 1);
    const int pid0 = b * EPB + e0;

    float l = 0.f;
    float acc[8];
#pragma unroll
    for (int i = 0; i < 8; ++i) acc[i] = 0.f;
    for (int cc = 0; cc < nc; ++cc) {
        l += pl[(pid0 + cc) * 64 + lr];
        short8 p8 = *(const short8*)(po + (size_t)(pid0 + cc) * 4096 + lr * 64 + h8 * 8);
#pragma unroll
        for (int i = 0; i < 8; ++i) acc[i] += bf2f((unsigned short)p8[i]);
    }
    float inv = 1.f / l;
    float4 r0 = make_float4(acc[0] * inv, acc[1] * inv, acc[2] * inv, acc[3] * inv);
    float4 r1 = make_float4(acc[4] * inv, acc[5] * inv, acc[6] * inv, acc[7] * inv);
    float* dst = out + (size_t)gth * 8;
    *(float4*)dst       = r0;
    *(float4*)(dst + 4) = r1;
}

extern "C" void kernel_launch(void* const* d_in, const int* in_sizes, int n_in,
                              void* d_out, int out_size, void* d_ws, size_t ws_size,
                              hipStream_t stream) {
    const float* x  = (const float*)d_in[0];
    const float* Wq = (const float*)d_in[1];
    const float* Wk = (const float*)d_in[2];
    const float* Wv = (const float*)d_in[3];
    float* out = (float*)d_out;

    char* ws = (char*)d_ws;
    unsigned short* qb = (unsigned short*)(ws);                 // 2 MB
    unsigned short* kb = (unsigned short*)(ws + (2u << 20));    // 2 MB
    unsigned short* vt = (unsigned short*)(ws + (4u << 20));    // 2 MB
    unsigned short* wt = (unsigned short*)(ws + (6u << 20));    // 192 KB
    float* pl = (float*)(ws + (6u << 20) + 196608);             // 294912 B
    unsigned short* po = (unsigned short*)(ws + (6u << 20) + 196608 + 294912); // 9.4 MB

    wcvt_kernel<<<dim3(192), dim3(64), 0, stream>>>(Wq, Wk, Wv, wt);
    proj_kernel<<<dim3(512), dim3(512), 0, stream>>>(x, wt, qb, kb, vt);
    attn1_kernel<<<dim3(NBATCH * EPB), dim3(256), 0, stream>>>(qb, kb, vt, po, pl);
    combine_kernel<<<dim3(512), dim3(256), 0, stream>>>(po, pl, out);
}

// Round 13
// 110.413 us; speedup vs baseline: 1.4061x; 1.0227x over previous
//
#include <hip/hip_runtime.h>
#include <hip/hip_bf16.h>
#include <math.h>

#define T_SEQ 4096
#define NBATCH 4
#define C_EMB 512
#define HEAD 64
#define CHUNK 8                  // k-tiles (of 64) per attn phase-1 block
#define EPB 288                  // per batch: sum over qt of ceil((qt+1)/8)

typedef __attribute__((ext_vector_type(8))) short short8;
typedef __attribute__((ext_vector_type(4))) short short4v;
typedef __attribute__((ext_vector_type(4))) float f32x4;

// scale folded into q at projection: exp(s/sqrt(512)) = exp2(qhat . k)
#define C2 (0.044194173824159216f * 1.44269504088896340736f)

__device__ __forceinline__ unsigned short f2bf(float f) {
    union { float f; unsigned u; } v; v.f = f;
    unsigned u = v.u;
    u += 0x7FFF + ((u >> 16) & 1);   // round-to-nearest-even
    return (unsigned short)(u >> 16);
}
// packed f32x2 -> bf16x2 (v_cvt_pk_bf16_f32); low 16 = a, high 16 = b
__device__ __forceinline__ unsigned pk2bf(float a, float b) {
    __hip_bfloat162 h = __float22bfloat162_rn(make_float2(a, b));
    return *(unsigned*)&h;
}
__device__ __forceinline__ float bf2f(unsigned short u) {
    union { unsigned u; float f; } v; v.u = ((unsigned)u) << 16;
    return v.f;
}

// async global->LDS, 16 B per lane; LDS dest = wave-uniform base + lane*16
#define GLD_LDS16(gp, lp)                                                     \
    __builtin_amdgcn_global_load_lds(                                         \
        (const __attribute__((address_space(1))) void*)(gp),                  \
        (__attribute__((address_space(3))) void*)(lp), 16, 0, 0)

// ---------------- W conversion: emit the per-chunk LDS image ------------------
// wt2 short index: (((c*12 + tile)*2 + kc)*64 + lane)*8 + i  holds
// bf16(W_w[k][n]), w=tile>>2, n=(tile&3)*16+(lane&15), k=c*64+kc*32+(lane>>4)*8+i.
// Lane's 16 B IS its MFMA B-fragment -> staged LDS reads are conflict-free.
__global__ __launch_bounds__(64) void wcvt_kernel(
    const float* __restrict__ Wq, const float* __restrict__ Wk,
    const float* __restrict__ Wv, unsigned short* __restrict__ wt2)
{
    const int gid  = blockIdx.x * 64 + threadIdx.x;   // 0..12287
    const int lane = gid & 63;
    int rest = gid >> 6;
    const int kc   = rest & 1; rest >>= 1;
    const int tile = rest % 12;
    const int c    = rest / 12;
    const float* W = (tile < 4) ? Wq : (tile < 8) ? Wk : Wv;
    const int n  = (tile & 3) * 16 + (lane & 15);
    const int k0 = c * 64 + kc * 32 + (lane >> 4) * 8;
    unsigned short tmp[8];
#pragma unroll
    for (int i = 0; i < 8; ++i) tmp[i] = f2bf(W[(size_t)(k0 + i) * HEAD + n]);
    *(short8*)(wt2 + (size_t)gid * 8) = *(short8*)tmp;
}

// ---------------- Projection v5: global_load_lds W staging --------------------
// grid 512 x 512thr; block = 32 x-rows, 2 blocks/CU (LDS 58.4 KB). 8 waves
// split 24 (M-quarter x N-tile) jobs; W chunk (24 KB) staged direct-to-LDS via
// 3 global_load_lds_dwordx4 per wave (no VGPR round-trip, conflict-free image).
__global__ __launch_bounds__(512, 4) void proj_kernel(
    const float* __restrict__ x,            // [16384, 512]
    const unsigned short* __restrict__ wt2, // [8][12][2][64][8] bf16
    unsigned short* __restrict__ qout,      // [16384, 64]  (pre-scaled by C2)
    unsigned short* __restrict__ kout,      // [16384, 64]
    unsigned short* __restrict__ vt)        // [4][64][4096]
{
    __shared__ unsigned short Wl[2][12288];     // 49152 B, per-chunk image
    __shared__ unsigned short Xl[2][32][72];    //  9216 B (reused as Vsh[64][40])

    const int tid  = threadIdx.x;
    const int wave = tid >> 6;
    const int lane = tid & 63;
    const int l16  = lane & 15;
    const int quad = lane >> 4;
    const int row0 = blockIdx.x * 32;
    const int mq   = wave & 1;           // M-quarter (16 rows)
    const int ng   = wave >> 1;          // N-group: tiles ng*3 .. ng*3+2

    const bool xst = tid < 256;
    const int xrow = tid >> 3;           // x row (tid<256)
    const int xc8  = (tid & 7) * 8;

    f32x4 acc[3];
#pragma unroll
    for (int j = 0; j < 3; ++j) acc[j] = (f32x4){0.f, 0.f, 0.f, 0.f};

    // ---- stage chunk 0 into buffer 0 ----
#pragma unroll
    for (int m = 0; m < 3; ++m)
        GLD_LDS16(wt2 + (size_t)(m * 4096 + wave * 512 + lane * 8),
                  &Wl[0][m * 4096 + wave * 512]);
    if (xst) {
        const float* xs = x + (size_t)(row0 + xrow) * C_EMB + xc8;
        float4 a = *(const float4*)(xs);
        float4 b = *(const float4*)(xs + 4);
        int4 ai = make_int4((int)pk2bf(a.x, a.y), (int)pk2bf(a.z, a.w),
                            (int)pk2bf(b.x, b.y), (int)pk2bf(b.z, b.w));
        *(short8*)&Xl[0][xrow][xc8] = *(short8*)&ai;
    }
    __syncthreads();

    for (int c = 0; c < 8; ++c) {
        const int bb = c & 1;
        if (c < 7) {                     // stage chunk c+1 into other buffer
            const int nb = bb ^ 1;
            const size_t g0 = (size_t)(c + 1) * 12288;
#pragma unroll
            for (int m = 0; m < 3; ++m)
                GLD_LDS16(wt2 + g0 + (size_t)(m * 4096 + wave * 512 + lane * 8),
                          &Wl[nb][m * 4096 + wave * 512]);
            if (xst) {
                const float* xs = x + (size_t)(row0 + xrow) * C_EMB + (c + 1) * 64 + xc8;
                float4 a = *(const float4*)(xs);
                float4 b = *(const float4*)(xs + 4);
                int4 ai = make_int4((int)pk2bf(a.x, a.y), (int)pk2bf(a.z, a.w),
                                    (int)pk2bf(b.x, b.y), (int)pk2bf(b.z, b.w));
                *(short8*)&Xl[nb][xrow][xc8] = *(short8*)&ai;
            }
        }

        // compute on buffer bb: 2 kc x (1 A-frag, 3 B-frags, 3 MFMA)
#pragma unroll
        for (int kc = 0; kc < 2; ++kc) {
            short8 a0 = *(const short8*)&Xl[bb][mq * 16 + l16][kc * 32 + quad * 8];
#pragma unroll
            for (int j = 0; j < 3; ++j) {
                const int ct = ng * 3 + j;
                short8 bfr = *(const short8*)&Wl[bb][(ct * 128 + kc * 64 + lane) * 8];
                acc[j] = __builtin_amdgcn_mfma_f32_16x16x32_bf16(a0, bfr, acc[j], 0, 0, 0);
            }
        }
        __syncthreads();
    }

    // epilogue: wave owns (mq, tiles ng*3..ng*3+2); tile ct: m=ct>>2, n=ct&3
    unsigned short (*Vsh)[40] = (unsigned short (*)[40]) & Xl[0][0][0];  // 5120 B
#pragma unroll
    for (int j = 0; j < 3; ++j) {
        const int ct = ng * 3 + j;
        const int m  = ct >> 2;
        const int n  = ct & 3;
#pragma unroll
        for (int r = 0; r < 4; ++r) {
            const int row = row0 + mq * 16 + quad * 4 + r;
            if (m == 0)
                qout[(size_t)row * HEAD + n * 16 + l16] = f2bf(acc[j][r] * C2);
            else if (m == 1)
                kout[(size_t)row * HEAD + n * 16 + l16] = f2bf(acc[j][r]);
            else
                Vsh[n * 16 + l16][mq * 16 + quad * 4 + r] = f2bf(acc[j][r]);
        }
    }
    __syncthreads();
    if (tid < 256) {
        int h  = tid >> 2;
        int tc = (tid & 3) * 8;
        int b  = row0 >> 12;
        int t0 = row0 & (T_SEQ - 1);
        unsigned short* dst = vt + ((size_t)(b * HEAD + h)) * T_SEQ + t0 + tc;
        *(short8*)dst = *(const short8*)&Vsh[h][tc];
    }
}

// stage one V row-chunk (16 cols from sc) phi-swizzled:
// col c bits [s|d|q1 q0|r1 r0] -> position [s|q1 q0|d|r1 r0]
// so PV B-frags are single contiguous b128 reads matching the A-frag k-order.
__device__ __forceinline__ void stage_v(unsigned short (*Vbuf)[72], int sr, int phiA,
                                        short8 v0, short8 v1) {
    *(short4v*)&Vbuf[sr][phiA]      = __builtin_shufflevector(v0, v0, 0, 1, 2, 3);
    *(short4v*)&Vbuf[sr][phiA + 8]  = __builtin_shufflevector(v0, v0, 4, 5, 6, 7);
    *(short4v*)&Vbuf[sr][phiA + 16] = __builtin_shufflevector(v1, v1, 0, 1, 2, 3);
    *(short4v*)&Vbuf[sr][phiA + 24] = __builtin_shufflevector(v1, v1, 4, 5, 6, 7);
}

// ---------------- Attention phase 1: S^T trick, no P LDS round-trip ----------
__global__ __launch_bounds__(256) void attn1_kernel(
    const unsigned short* __restrict__ qb,  // [B*T, 64] pre-scaled
    const unsigned short* __restrict__ kb,  // [B*T, 64]
    const unsigned short* __restrict__ vt,  // [4][64][4096]
    unsigned short* __restrict__ po,        // [1152][64][64] bf16 partials
    float* __restrict__ pl)                 // [1152][64]
{
    __shared__ unsigned short Ks[2][64][72];    // [buf][kpos][h]
    __shared__ unsigned short Vs[2][64][72];    // [buf][h][phi(kpos)]

    const int tid  = threadIdx.x;
    const int wave = tid >> 6;
    const int lane = tid & 63;
    const int l16  = lane & 15;
    const int quad = lane >> 4;

    const int b = blockIdx.x / EPB;
    const int e = blockIdx.x % EPB;
    // decode e -> (qt, c): group g has qt in [8g,8g+8), nc=g+1, base 4g(g+1)
    int g = 0;
#pragma unroll
    for (int gg = 1; gg < 8; ++gg) if (e >= 4 * gg * (gg + 1)) g = gg;
    const int rem = e - 4 * g * (g + 1);
    const int t   = rem / (g + 1);
    const int c   = rem - t * (g + 1);
    const int qt  = 8 * g + t;

    const size_t base = (size_t)b * T_SEQ;
    const int qrow = qt * 64 + wave * 16 + l16;
    short8 aq0 = *(const short8*)(qb + (base + qrow) * HEAD + quad * 8);
    short8 aq1 = *(const short8*)(qb + (base + qrow) * HEAD + 32 + quad * 8);

    float lacc = 0.f;
    f32x4 o[4];
#pragma unroll
    for (int n = 0; n < 4; ++n) o[n] = (f32x4){0.f, 0.f, 0.f, 0.f};

    const int kt0 = c * CHUNK;
    const int np  = min(CHUNK, qt + 1 - kt0);   // 1..8 64-wide iterations

    const int sr   = tid >> 2;            // 0..63
    const int sc   = (tid & 3) * 16;      // 0,16,32,48
    const int phiA = (sc & 32) + ((sc & 16) >> 2);

    short8 kra, krb, vra, vrb;
    {
        const int kbase = kt0 * 64;
        const unsigned short* ksrc = kb + (base + kbase + sr) * HEAD + sc;
        const unsigned short* vsrc = vt + ((size_t)(b * HEAD + sr)) * T_SEQ + kbase + sc;
        kra = *(const short8*)(ksrc);     krb = *(const short8*)(ksrc + 8);
        vra = *(const short8*)(vsrc);     vrb = *(const short8*)(vsrc + 8);
    }
    *(short8*)&Ks[0][sr][sc]     = kra;  *(short8*)&Ks[0][sr][sc + 8] = krb;
    stage_v(Vs[0], sr, phiA, vra, vrb);

    for (int p = 0; p < np; ++p) {
        const int cur = p & 1;
        const int kbase = (kt0 + p) * 64;
        __syncthreads();                 // LDS[cur] ready; prev-iter reads done

        if (p + 1 < np) {                // prefetch next tile into regs
            const int nb = kbase + 64;
            const unsigned short* ksrc = kb + (base + nb + sr) * HEAD + sc;
            const unsigned short* vsrc = vt + ((size_t)(b * HEAD + sr)) * T_SEQ + nb + sc;
            kra = *(const short8*)(ksrc);  krb = *(const short8*)(ksrc + 8);
            vra = *(const short8*)(vsrc);  vrb = *(const short8*)(vsrc + 8);
        }

        // S^T = K.Q^T: lane gets S[q=l16][c = kbase + n*16 + quad*4 + r]
        f32x4 s[4];
#pragma unroll
        for (int n = 0; n < 4; ++n) {
            short8 bk0 = *(const short8*)&Ks[cur][n * 16 + l16][quad * 8];
            short8 bk1 = *(const short8*)&Ks[cur][n * 16 + l16][32 + quad * 8];
            f32x4 accS = (f32x4){0.f, 0.f, 0.f, 0.f};
            accS = __builtin_amdgcn_mfma_f32_16x16x32_bf16(bk0, aq0, accS, 0, 0, 0);
            accS = __builtin_amdgcn_mfma_f32_16x16x32_bf16(bk1, aq1, accS, 0, 0, 0);
            s[n] = accS;
        }

        // P = exp2(S); zero masked cols on the diagonal tile (wave-uniform test)
#pragma unroll
        for (int n = 0; n < 4; ++n)
#pragma unroll
            for (int r = 0; r < 4; ++r)
                s[n][r] = __builtin_amdgcn_exp2f(s[n][r]);

        if (kbase + 64 > qt * 64) {
            const int cb = kbase + quad * 4;
#pragma unroll
            for (int n = 0; n < 4; ++n)
#pragma unroll
                for (int r = 0; r < 4; ++r)
                    if (cb + n * 16 + r > qrow) s[n][r] = 0.f;
        }

#pragma unroll
        for (int n = 0; n < 4; ++n)
            lacc += (s[n][0] + s[n][1]) + (s[n][2] + s[n][3]);

        // PV: pack A-frag locally (k-order matches phi-swizzled V), B = b128
#pragma unroll
        for (int st = 0; st < 2; ++st) {
            int4 ai = make_int4(
                (int)pk2bf(s[2 * st][0],     s[2 * st][1]),
                (int)pk2bf(s[2 * st][2],     s[2 * st][3]),
                (int)pk2bf(s[2 * st + 1][0], s[2 * st + 1][1]),
                (int)pk2bf(s[2 * st + 1][2], s[2 * st + 1][3]));
            short8 af = *(short8*)&ai;
#pragma unroll
            for (int n = 0; n < 4; ++n) {
                short8 bv = *(const short8*)&Vs[cur][n * 16 + l16][32 * st + quad * 8];
                o[n] = __builtin_amdgcn_mfma_f32_16x16x32_bf16(af, bv, o[n], 0, 0, 0);
            }
        }

        if (p + 1 < np) {                // stage next tile into the other buffer
            const int nxt = cur ^ 1;
            *(short8*)&Ks[nxt][sr][sc]     = kra;  *(short8*)&Ks[nxt][sr][sc + 8] = krb;
            stage_v(Vs[nxt], sr, phiA, vra, vrb);
        }
    }

    // reduce l over the quad dimension (q-row = l16 per lane)
    lacc += __shfl_xor(lacc, 16);
    lacc += __shfl_xor(lacc, 32);

    const int pid = blockIdx.x;
#pragma unroll
    for (int n = 0; n < 4; ++n)
#pragma unroll
        for (int r = 0; r < 4; ++r) {
            int lr = wave * 16 + quad * 4 + r;
            po[(size_t)pid * 4096 + lr * 64 + n * 16 + l16] = f2bf(o[n][r]);
        }
    if (quad == 0)
        pl[pid * 64 + wave * 16 + l16] = lacc;
}

// ---------------- Combine: sum <=8 bf16 partials, normalize ----------------
__global__ __launch_bounds__(256) void combine_kernel(
    const unsigned short* __restrict__ po, const float* __restrict__ pl,
    float* __restrict__ out)
{
    const int gth = blockIdx.x * 256 + threadIdx.x;   // octet index, 131072 total
    const int h8  = gth & 7;
    const int row = gth >> 3;
    const int lr  = row & 63;
    const int qt  = (row >> 6) & 63;
    const int b   = row >> 12;
    const int nc  = (qt >> 3) + 1;
    const int g   = qt >> 3;
    const int rem = qt & 7;
    const int e0  = 4 * g * (g + 1) + rem * (g + 1);
    const int pid0 = b * EPB + e0;

    float l = 0.f;
    float acc[8];
#pragma unroll
    for (int i = 0; i < 8; ++i) acc[i] = 0.f;
    for (int cc = 0; cc < nc; ++cc) {
        l += pl[(pid0 + cc) * 64 + lr];
        short8 p8 = *(const short8*)(po + (size_t)(pid0 + cc) * 4096 + lr * 64 + h8 * 8);
#pragma unroll
        for (int i = 0; i < 8; ++i) acc[i] += bf2f((unsigned short)p8[i]);
    }
    float inv = 1.f / l;
    float4 r0 = make_float4(acc[0] * inv, acc[1] * inv, acc[2] * inv, acc[3] * inv);
    float4 r1 = make_float4(acc[4] * inv, acc[5] * inv, acc[6] * inv, acc[7] * inv);
    float* dst = out + (size_t)gth * 8;
    *(float4*)dst       = r0;
    *(float4*)(dst + 4) = r1;
}

extern "C" void kernel_launch(void* const* d_in, const int* in_sizes, int n_in,
                              void* d_out, int out_size, void* d_ws, size_t ws_size,
                              hipStream_t stream) {
    const float* x  = (const float*)d_in[0];
    const float* Wq = (const float*)d_in[1];
    const float* Wk = (const float*)d_in[2];
    const float* Wv = (const float*)d_in[3];
    float* out = (float*)d_out;

    char* ws = (char*)d_ws;
    unsigned short* qb = (unsigned short*)(ws);                 // 2 MB
    unsigned short* kb = (unsigned short*)(ws + (2u << 20));    // 2 MB
    unsigned short* vt = (unsigned short*)(ws + (4u << 20));    // 2 MB
    unsigned short* wt2 = (unsigned short*)(ws + (6u << 20));   // 192 KB
    float* pl = (float*)(ws + (6u << 20) + 196608);             // 294912 B
    unsigned short* po = (unsigned short*)(ws + (6u << 20) + 196608 + 294912); // 9.4 MB

    wcvt_kernel<<<dim3(192), dim3(64), 0, stream>>>(Wq, Wk, Wv, wt2);
    proj_kernel<<<dim3(512), dim3(512), 0, stream>>>(x, wt2, qb, kb, vt);
    attn1_kernel<<<dim3(NBATCH * EPB), dim3(256), 0, stream>>>(qb, kb, vt, po, pl);
    combine_kernel<<<dim3(512), dim3(256), 0, stream>>>(po, pl, out);
}